// Round 5
// baseline (214.111 us; speedup 1.0000x reference)
//
#include <hip/hip_runtime.h>
#include <hip/hip_bf16.h>
#include <float.h>

#define N 8192
#define D 128
#define WAVES 8
#define BM 512                       // rows per block: 8 waves x 64
#define BN 64                        // cols per LDS tile
#define GY 32                        // col-chunks (grid.y)
#define COLS_PER_BLOCK (N / GY)      // 256
#define TILES (COLS_PER_BLOCK / BN)  // 4
#define NPART GY                     // 32 partial slots per row
#define LOSS_BLOCKS (N / 256)        // 32

typedef unsigned short u16;
typedef unsigned int u32;
typedef __attribute__((ext_vector_type(8))) short bf16x8;
typedef __attribute__((ext_vector_type(4))) float f32x4;

typedef const __attribute__((address_space(1))) u32 glb_u32;
typedef __attribute__((address_space(3))) u32 lds_u32;

__device__ inline u16 f32_to_bf16_rtne(float f) {
  union { float f; unsigned int u; } c; c.f = f;
  unsigned int u = c.u;
  u += 0x7FFFu + ((u >> 16) & 1u);
  return (u16)(u >> 16);
}

// ---------------- kernel 1: f32 -> bf16 convert ----------------
__global__ __launch_bounds__(256) void convert_kernel(const float* __restrict__ P,
                                                      u16* __restrict__ Pb) {
  int i = blockIdx.x * 256 + threadIdx.x;
  float4 v = reinterpret_cast<const float4*>(P)[i];
  uint2 o;
  o.x = (unsigned)f32_to_bf16_rtne(v.x) | ((unsigned)f32_to_bf16_rtne(v.y) << 16);
  o.y = (unsigned)f32_to_bf16_rtne(v.z) | ((unsigned)f32_to_bf16_rtne(v.w) << 16);
  reinterpret_cast<uint2*>(Pb)[i] = o;
}

// ---------------- kernel 2 body: 3-deep pipelined fused sim + min/max ----------
// 8 waves x 64 rows (4 rowgroups). B tile 64 cols shared by all waves: 16 b128
// feed 16 MFMAs (4x reuse). Swizzle (validated r2-r4):
// LDS_off(c,o) = c*256 + (o ^ ((c&15)<<4)), applied on global SOURCE at stage
// time and on the ds_read address (rule 21).
template <bool DIAG>
__device__ __forceinline__ void pipeline(const char* __restrict__ pbb,
                                         const int* __restrict__ y,
                                         float* __restrict__ pmin,
                                         float* __restrict__ pmax,
                                         char* ldsB, int* ldsY,
                                         int R0, int C0, int slot) {
  const int tid  = threadIdx.x;
  const int w    = tid >> 6;         // 0..7
  const int lane = tid & 63;
  const int c15  = lane & 15;
  const int g    = lane >> 4;

  // y for the block's 256 cols: waves 0-3 load 64 ints each
  if (w < 4)
    __builtin_amdgcn_global_load_lds((glb_u32*)(y + C0 + w * 64 + lane),
                                     (lds_u32*)(ldsY + w * 64), 4, 0, 0);

  // stage tile t: 16KB, 2 glds x 1KB per wave (uniform count for vmcnt math)
  auto STAGE = [&](int buf, int t) {
    const char* gb = pbb + (size_t)(C0 + t * BN) * 256;
    char* base = ldsB + buf * (BN * 256);
#pragma unroll
    for (int j = 0; j < 2; ++j) {
      const int L = ((w * 2 + j) * 64 + lane) * 16;    // linear LDS byte
      const int c = L >> 8;
      const int o = L & 255;
      const int src = c * 256 + (o ^ ((c & 15) << 4)); // inverse-swizzled source
      __builtin_amdgcn_global_load_lds((glb_u32*)(gb + src),
                                       (lds_u32*)(base + (w * 2 + j) * 1024), 16, 0, 0);
    }
  };

  STAGE(0, 0);
  STAGE(1, 1);

  const int rowbase = R0 + w * 64 + g * 4;   // + rg*16 + r

  // A fragments: 4 rowgroups x 16 rows, K=128 (64 VGPRs, resident)
  bf16x8 afrag[4][4];
#pragma unroll
  for (int rg = 0; rg < 4; ++rg) {
    const char* ap = pbb + (size_t)(R0 + w * 64 + rg * 16 + c15) * 256 + g * 16;
#pragma unroll
    for (int kk = 0; kk < 4; ++kk)
      afrag[rg][kk] = *reinterpret_cast<const bf16x8*>(ap + kk * 64);
  }

  int yrow[4][4];
#pragma unroll
  for (int rg = 0; rg < 4; ++rg)
#pragma unroll
    for (int r = 0; r < 4; ++r)
      yrow[rg][r] = y[rowbase + rg * 16 + r];

  float mins[4][4], maxd[4][4];
#pragma unroll
  for (int rg = 0; rg < 4; ++rg)
#pragma unroll
    for (int r = 0; r < 4; ++r) { mins[rg][r] = FLT_MAX; maxd[rg][r] = -FLT_MAX; }

#pragma unroll 1
  for (int t = 0; t < TILES; ++t) {
    // counted vmcnt: stage(t) drained (FIFO), stage(t+1)'s 2 loads in flight
    if (t + 1 < TILES) asm volatile("s_waitcnt vmcnt(2)" ::: "memory");
    else               asm volatile("s_waitcnt vmcnt(0)" ::: "memory");
    __builtin_amdgcn_s_barrier();          // all waves' stage(t) landed;
                                           // buf[(t+2)%3] free (was read in t-1)
    if (t + 2 < TILES) STAGE((t + 2) % 3, t + 2);

    const char* Bb = ldsB + (t % 3) * (BN * 256);
#pragma unroll
    for (int s = 0; s < 4; ++s) {
      const int c = s * 16 + c15;
      const int colB = t * BN + c;
      const int ycol = ldsY[colB];
      bf16x8 bf[4];
#pragma unroll
      for (int kk = 0; kk < 4; ++kk) {
        const int off = c * 256 + (((g * 16) | (kk * 64)) ^ (c15 << 4));
        bf[kk] = *reinterpret_cast<const bf16x8*>(Bb + off);
      }
      const int col = C0 + colB;
#pragma unroll
      for (int rg = 0; rg < 4; ++rg) {       // per-rg: 4-MFMA chain then epilogue
        f32x4 acc = {0.f, 0.f, 0.f, 0.f};
        __builtin_amdgcn_s_setprio(1);
#pragma unroll
        for (int kk = 0; kk < 4; ++kk)
          acc = __builtin_amdgcn_mfma_f32_16x16x32_bf16(afrag[rg][kk], bf[kk], acc, 0, 0, 0);
        __builtin_amdgcn_s_setprio(0);
#pragma unroll
        for (int r = 0; r < 4; ++r) {
          const float v = acc[r];
          const bool same = (ycol == yrow[rg][r]);
          bool okmin = same;
          if (DIAG) okmin = same && (col != rowbase + rg * 16 + r);
          mins[rg][r] = fminf(mins[rg][r], okmin ? v : FLT_MAX);
          maxd[rg][r] = fmaxf(maxd[rg][r], same ? -FLT_MAX : v);
        }
      }
    }
  }

  // butterfly over the 16 col-lanes (bits 0-3; stays within g-group)
#pragma unroll
  for (int off = 1; off < 16; off <<= 1)
#pragma unroll
    for (int rg = 0; rg < 4; ++rg)
#pragma unroll
      for (int r = 0; r < 4; ++r) {
        mins[rg][r] = fminf(mins[rg][r], __shfl_xor(mins[rg][r], off, 64));
        maxd[rg][r] = fmaxf(maxd[rg][r], __shfl_xor(maxd[rg][r], off, 64));
      }

  if (c15 == 0) {
#pragma unroll
    for (int rg = 0; rg < 4; ++rg)
#pragma unroll
      for (int r = 0; r < 4; ++r) {
        pmin[(size_t)slot * N + rowbase + rg * 16 + r] = mins[rg][r];
        pmax[(size_t)slot * N + rowbase + rg * 16 + r] = maxd[rg][r];
      }
  }
}

__global__ __launch_bounds__(512, 4) void margin_main(const u16* __restrict__ Pb,
                                                      const int* __restrict__ y,
                                                      float* __restrict__ pmin,
                                                      float* __restrict__ pmax) {
  __shared__ __align__(16) char ldsB[3][BN * 256];   // 48 KB, 3-deep
  __shared__ int ldsY[COLS_PER_BLOCK];               // 1 KB
  const int R0 = blockIdx.x * BM;
  const int C0 = blockIdx.y * COLS_PER_BLOCK;
  if ((unsigned)(C0 - R0) < (unsigned)BM)            // block contains diagonal
    pipeline<true>((const char*)Pb, y, pmin, pmax, &ldsB[0][0], ldsY, R0, C0, blockIdx.y);
  else
    pipeline<false>((const char*)Pb, y, pmin, pmax, &ldsB[0][0], ldsY, R0, C0, blockIdx.y);
}

// ---------------- kernel 3: combine partials, hinge, block sums ----------------
__global__ __launch_bounds__(256) void loss_kernel(const float* __restrict__ pmin,
                                                   const float* __restrict__ pmax,
                                                   float* __restrict__ blockSums) {
  const int row = blockIdx.x * 256 + threadIdx.x;
  float mn = FLT_MAX, mx = -FLT_MAX;
#pragma unroll
  for (int s = 0; s < NPART; ++s) {            // slot-major: coalesced
    mn = fminf(mn, pmin[(size_t)s * N + row]);
    mx = fmaxf(mx, pmax[(size_t)s * N + row]);
  }
  if (mn == FLT_MAX)  mn = 0.f;
  if (mx == -FLT_MAX) mx = 0.f;
  float loss = fmaxf(0.f, mn + mx + 1.0f);     // TAU = 1.0

#pragma unroll
  for (int off = 32; off >= 1; off >>= 1)
    loss += __shfl_down(loss, off, 64);
  __shared__ float wsum[4];
  if ((threadIdx.x & 63) == 0) wsum[threadIdx.x >> 6] = loss;
  __syncthreads();
  if (threadIdx.x == 0)
    blockSums[blockIdx.x] = wsum[0] + wsum[1] + wsum[2] + wsum[3];
}

// ---------------- kernel 4: final mean ----------------
__global__ __launch_bounds__(64) void finalize_kernel(const float* __restrict__ blockSums,
                                                      float* __restrict__ out) {
  float v = (threadIdx.x < LOSS_BLOCKS) ? blockSums[threadIdx.x] : 0.f;
#pragma unroll
  for (int off = 32; off >= 1; off >>= 1)
    v += __shfl_down(v, off, 64);
  if (threadIdx.x == 0) out[0] = v / (float)N;
}

extern "C" void kernel_launch(void* const* d_in, const int* in_sizes, int n_in,
                              void* d_out, int out_size, void* d_ws, size_t ws_size,
                              hipStream_t stream) {
  const float* P = (const float*)d_in[0];
  const int*   y = (const int*)d_in[1];
  float* out = (float*)d_out;

  // ws: Pb (2MB) | pmin (1MB) | pmax (1MB) | blockSums
  u16*   Pb        = (u16*)d_ws;
  float* pmin      = (float*)((char*)d_ws + (size_t)N * D * sizeof(u16));
  float* pmax      = pmin + (size_t)N * NPART;
  float* blockSums = pmax + (size_t)N * NPART;

  convert_kernel<<<dim3(N * D / 4 / 256), 256, 0, stream>>>(P, Pb);
  margin_main<<<dim3(N / BM, GY), 512, 0, stream>>>(Pb, y, pmin, pmax);
  loss_kernel<<<dim3(LOSS_BLOCKS), 256, 0, stream>>>(pmin, pmax, blockSums);
  finalize_kernel<<<1, 64, 0, stream>>>(blockSums, out);
}

// Round 6
// 100.132 us; speedup vs baseline: 2.1383x; 2.1383x over previous
//
#include <hip/hip_runtime.h>
#include <hip/hip_bf16.h>
#include <float.h>

#define N 8192
#define D 128
#define BS 128                        // superblock edge (rows=cols per block)
#define NB (N / BS)                   // 64
#define TRI_BLOCKS (NB * (NB + 1) / 2)  // 2080
#define LOSS_BLOCKS (N / 256)         // 32

typedef unsigned short u16;
typedef unsigned int u32;
typedef __attribute__((ext_vector_type(8))) short bf16x8;
typedef __attribute__((ext_vector_type(4))) float f32x4;

typedef const __attribute__((address_space(1))) u32 glb_u32;
typedef __attribute__((address_space(3))) u32 lds_u32;

// monotonic float<->u32 map: order on u32 == order on float
__device__ __forceinline__ u32 fmap(float x) {
  u32 u = __float_as_uint(x);
  return (u >> 31) ? ~u : (u | 0x80000000u);
}
__device__ __forceinline__ float funmap(u32 m) {
  u32 u = (m & 0x80000000u) ? (m ^ 0x80000000u) : ~m;
  return __uint_as_float(u);
}
#define SENT_MIN 0xFF7FFFFFu   // fmap(+FLT_MAX)
#define SENT_MAX 0x00800000u   // fmap(-FLT_MAX)

__device__ __forceinline__ u16 f32_to_bf16_rtne(float f) {
  u32 u = __float_as_uint(f);
  u += 0x7FFFu + ((u >> 16) & 1u);
  return (u16)(u >> 16);
}

// ------------- kernel 1: f32 -> bf16 convert + atomic-array init -------------
__global__ __launch_bounds__(256) void convert_kernel(const float* __restrict__ P,
                                                      u16* __restrict__ Pb,
                                                      u32* __restrict__ pminU,
                                                      u32* __restrict__ pmaxU) {
  int i = blockIdx.x * 256 + threadIdx.x;
  float4 v = reinterpret_cast<const float4*>(P)[i];
  uint2 o;
  o.x = (unsigned)f32_to_bf16_rtne(v.x) | ((unsigned)f32_to_bf16_rtne(v.y) << 16);
  o.y = (unsigned)f32_to_bf16_rtne(v.z) | ((unsigned)f32_to_bf16_rtne(v.w) << 16);
  reinterpret_cast<uint2*>(Pb)[i] = o;
  if (blockIdx.x < 32) {                       // init 8192 entries of each array
    int k = blockIdx.x * 256 + threadIdx.x;
    pminU[k] = SENT_MIN;
    pmaxU[k] = SENT_MAX;
  }
}

// ------------- kernel 2: symmetric fused sim + masked min/max ----------------
// One block per upper-triangle 128x128 superblock (incl. diagonal). 4 waves x
// 32 rows. Cols staged to LDS in 2 tiles of 64 (swizzle validated r2-r5:
// LDS_off(c,o) = c*256 + (o ^ ((c&15)<<4)), inverse applied on global source).
// Off-diag blocks update row stats AND (by symmetry) col stats; diag blocks
// compute their full square with row updates only (self excluded).
template <bool DIAG>
__device__ __forceinline__ void marginBody(const char* __restrict__ pbb,
                                           const int* __restrict__ y,
                                           u32* __restrict__ pminU,
                                           u32* __restrict__ pmaxU,
                                           char* ldsB, int* ldsY,
                                           float* ldsColMin, float* ldsColMax,
                                           int R0, int C0) {
  const int tid  = threadIdx.x;
  const int w    = tid >> 6;         // 0..3
  const int lane = tid & 63;
  const int c15  = lane & 15;
  const int g    = lane >> 4;

  // stage both 64-col tiles (no mid-loop staging, no mid-loop barriers)
#pragma unroll
  for (int t = 0; t < 2; ++t) {
    const char* gb = pbb + (size_t)(C0 + t * 64) * 256;
    char* base = ldsB + t * (64 * 256);
#pragma unroll
    for (int j = 0; j < 4; ++j) {
      const int L = ((w * 4 + j) * 64 + lane) * 16;    // linear LDS byte
      const int c = L >> 8;
      const int o = L & 255;
      const int src = c * 256 + (o ^ ((c & 15) << 4)); // inverse-swizzled src
      __builtin_amdgcn_global_load_lds((glb_u32*)(gb + src),
                                       (lds_u32*)(base + (w * 4 + j) * 1024), 16, 0, 0);
    }
  }
  // per-wave private copy of the 128 col classes (no cross-wave dependency)
  {
    const int* gy = y + C0 + lane;
    lds_u32* dst = (lds_u32*)(ldsY + w * 128);
    __builtin_amdgcn_global_load_lds((glb_u32*)gy,        dst,      4, 0, 0);
    __builtin_amdgcn_global_load_lds((glb_u32*)(gy + 64), dst + 64, 4, 0, 0);
  }

  const int rowbase = R0 + w * 32 + g * 4;   // + rg*16 + r

  // A fragments: 2 rowgroups x 16 rows, K=128 (32 VGPRs)
  bf16x8 afrag[2][4];
#pragma unroll
  for (int rg = 0; rg < 2; ++rg) {
    const char* ap = pbb + (size_t)(R0 + w * 32 + rg * 16 + c15) * 256 + g * 16;
#pragma unroll
    for (int kk = 0; kk < 4; ++kk)
      afrag[rg][kk] = *reinterpret_cast<const bf16x8*>(ap + kk * 64);
  }

  int yrow[2][4];
#pragma unroll
  for (int rg = 0; rg < 2; ++rg)
#pragma unroll
    for (int r = 0; r < 4; ++r)
      yrow[rg][r] = y[rowbase + rg * 16 + r];

  float rmin[2][4], rmax[2][4];
#pragma unroll
  for (int rg = 0; rg < 2; ++rg)
#pragma unroll
    for (int r = 0; r < 4; ++r) { rmin[rg][r] = FLT_MAX; rmax[rg][r] = -FLT_MAX; }

  __syncthreads();                    // drains vmcnt: all staging visible

  int* myY = ldsY + w * 128;
#pragma unroll
  for (int t = 0; t < 2; ++t) {
    const char* Bb = ldsB + t * (64 * 256);
#pragma unroll
    for (int s = 0; s < 4; ++s) {
      const int c = s * 16 + c15;            // col within tile
      const int colB = t * 64 + c;           // col within block (0..127)
      bf16x8 bf[4];
#pragma unroll
      for (int kk = 0; kk < 4; ++kk) {
        const int off = c * 256 + (((g * 16) | (kk * 64)) ^ (c15 << 4));
        bf[kk] = *reinterpret_cast<const bf16x8*>(Bb + off);
      }
      f32x4 acc0 = {0.f, 0.f, 0.f, 0.f}, acc1 = {0.f, 0.f, 0.f, 0.f};
      __builtin_amdgcn_s_setprio(1);
#pragma unroll
      for (int kk = 0; kk < 4; ++kk) {
        acc0 = __builtin_amdgcn_mfma_f32_16x16x32_bf16(afrag[0][kk], bf[kk], acc0, 0, 0, 0);
        acc1 = __builtin_amdgcn_mfma_f32_16x16x32_bf16(afrag[1][kk], bf[kk], acc1, 0, 0, 0);
      }
      __builtin_amdgcn_s_setprio(0);

      const int ycol = myY[colB];
      const int colg = C0 + colB;
      float cmn = FLT_MAX, cmx = -FLT_MAX;   // this col's candidates (this lane)
#pragma unroll
      for (int rg = 0; rg < 2; ++rg)
#pragma unroll
        for (int r = 0; r < 4; ++r) {
          const float v = (rg == 0) ? acc0[r] : acc1[r];
          const bool same = (ycol == yrow[rg][r]);
          bool okmin = same;
          if (DIAG) okmin = same && (colg != rowbase + rg * 16 + r);
          const float cnd_min = okmin ? v : FLT_MAX;
          const float cnd_max = same ? -FLT_MAX : v;
          rmin[rg][r] = fminf(rmin[rg][r], cnd_min);
          rmax[rg][r] = fmaxf(rmax[rg][r], cnd_max);
          if (!DIAG) {                        // symmetric col update
            cmn = fminf(cmn, cnd_min);
            cmx = fmaxf(cmx, cnd_max);
          }
        }
      if (!DIAG) {
        // reduce col candidates across the 4 row-groups (lanes 16 apart)
        cmn = fminf(cmn, __shfl_xor(cmn, 16, 64));
        cmn = fminf(cmn, __shfl_xor(cmn, 32, 64));
        cmx = fmaxf(cmx, __shfl_xor(cmx, 16, 64));
        cmx = fmaxf(cmx, __shfl_xor(cmx, 32, 64));
        if (g == 0) {                         // one writer per (wave, col)
          ldsColMin[w * 128 + colB] = cmn;
          ldsColMax[w * 128 + colB] = cmx;
        }
      }
    }
  }

  // row reduce: butterfly over the 16 col-lanes (bits 0-3)
#pragma unroll
  for (int off = 1; off < 16; off <<= 1)
#pragma unroll
    for (int rg = 0; rg < 2; ++rg)
#pragma unroll
      for (int r = 0; r < 4; ++r) {
        rmin[rg][r] = fminf(rmin[rg][r], __shfl_xor(rmin[rg][r], off, 64));
        rmax[rg][r] = fmaxf(rmax[rg][r], __shfl_xor(rmax[rg][r], off, 64));
      }
  if (c15 == 0) {
#pragma unroll
    for (int rg = 0; rg < 2; ++rg)
#pragma unroll
      for (int r = 0; r < 4; ++r) {
        const int row = rowbase + rg * 16 + r;
        atomicMin(&pminU[row], fmap(rmin[rg][r]));
        atomicMax(&pmaxU[row], fmap(rmax[rg][r]));
      }
  }

  if (!DIAG) {
    __syncthreads();                          // ldsCol* complete
    const int col   = tid & 127;
    const int which = tid >> 7;
    if (which == 0) {
      float v = fminf(fminf(ldsColMin[col], ldsColMin[128 + col]),
                      fminf(ldsColMin[256 + col], ldsColMin[384 + col]));
      atomicMin(&pminU[C0 + col], fmap(v));
    } else {
      float v = fmaxf(fmaxf(ldsColMax[col], ldsColMax[128 + col]),
                      fmaxf(ldsColMax[256 + col], ldsColMax[384 + col]));
      atomicMax(&pmaxU[C0 + col], fmap(v));
    }
  }
}

__global__ __launch_bounds__(256, 4) void margin_main(const u16* __restrict__ Pb,
                                                      const int* __restrict__ y,
                                                      u32* __restrict__ pminU,
                                                      u32* __restrict__ pmaxU) {
  __shared__ __align__(16) char ldsB[2][64 * 256];   // 32 KB
  __shared__ int   ldsY[4 * 128];                    // 2 KB (per-wave copies)
  __shared__ float ldsColMin[4 * 128];               // 2 KB
  __shared__ float ldsColMax[4 * 128];               // 2 KB

  // decode upper-triangle pair (bi <= bj) from linear block id
  const int t = blockIdx.x;
  int i = (int)((129.0f - sqrtf((float)(16641 - 8 * t))) * 0.5f);
  i = max(0, min(NB - 1, i));
  while (i * NB - i * (i - 1) / 2 > t) --i;
  while ((i + 1) * NB - (i + 1) * i / 2 <= t) ++i;
  const int j = i + (t - (i * NB - i * (i - 1) / 2));

  const int R0 = i * BS, C0 = j * BS;
  if (i == j)
    marginBody<true >((const char*)Pb, y, pminU, pmaxU, &ldsB[0][0], ldsY,
                      ldsColMin, ldsColMax, R0, C0);
  else
    marginBody<false>((const char*)Pb, y, pminU, pmaxU, &ldsB[0][0], ldsY,
                      ldsColMin, ldsColMax, R0, C0);
}

// ------------- kernel 3: hinge + block partial sums --------------------------
__global__ __launch_bounds__(256) void loss_kernel(const u32* __restrict__ pminU,
                                                   const u32* __restrict__ pmaxU,
                                                   float* __restrict__ blockSums) {
  const int row = blockIdx.x * 256 + threadIdx.x;
  const u32 um = pminU[row], ux = pmaxU[row];
  const float mn = (um == SENT_MIN) ? 0.f : funmap(um);
  const float mx = (ux == SENT_MAX) ? 0.f : funmap(ux);
  float loss = fmaxf(0.f, mn + mx + 1.0f);     // TAU = 1.0

#pragma unroll
  for (int off = 32; off >= 1; off >>= 1)
    loss += __shfl_down(loss, off, 64);
  __shared__ float wsum[4];
  if ((threadIdx.x & 63) == 0) wsum[threadIdx.x >> 6] = loss;
  __syncthreads();
  if (threadIdx.x == 0)
    blockSums[blockIdx.x] = wsum[0] + wsum[1] + wsum[2] + wsum[3];
}

// ------------- kernel 4: final mean ------------------------------------------
__global__ __launch_bounds__(64) void finalize_kernel(const float* __restrict__ blockSums,
                                                      float* __restrict__ out) {
  float v = (threadIdx.x < LOSS_BLOCKS) ? blockSums[threadIdx.x] : 0.f;
#pragma unroll
  for (int off = 32; off >= 1; off >>= 1)
    v += __shfl_down(v, off, 64);
  if (threadIdx.x == 0) out[0] = v / (float)N;
}

extern "C" void kernel_launch(void* const* d_in, const int* in_sizes, int n_in,
                              void* d_out, int out_size, void* d_ws, size_t ws_size,
                              hipStream_t stream) {
  const float* P = (const float*)d_in[0];
  const int*   y = (const int*)d_in[1];
  float* out = (float*)d_out;

  // ws: Pb (2MB) | pminU (32KB) | pmaxU (32KB) | blockSums
  u16* Pb        = (u16*)d_ws;
  u32* pminU     = (u32*)((char*)d_ws + (size_t)N * D * sizeof(u16));
  u32* pmaxU     = pminU + N;
  float* blockSums = (float*)(pmaxU + N);

  convert_kernel<<<dim3(N * D / 4 / 256), 256, 0, stream>>>(P, Pb, pminU, pmaxU);
  margin_main<<<dim3(TRI_BLOCKS), 256, 0, stream>>>(Pb, y, pminU, pmaxU);
  loss_kernel<<<dim3(LOSS_BLOCKS), 256, 0, stream>>>(pminU, pmaxU, blockSums);
  finalize_kernel<<<1, 64, 0, stream>>>(blockSums, out);
}

// Round 7
// 81.490 us; speedup vs baseline: 2.6275x; 1.2288x over previous
//
#include <hip/hip_runtime.h>
#include <hip/hip_bf16.h>
#include <float.h>

#define N 8192
#define D 128
#define BM 64                        // rows per block (shared by all 4 waves)
#define GY 16                        // col-chunks (grid.y)
#define WCOLS 128                    // cols per wave
#define NTILES 8                     // WCOLS / 16
#define NPART (GY * 4)               // 64 partial slots per row
#define LOSS_BLOCKS (N / 256)        // 32

typedef unsigned short u16;
typedef unsigned int u32;
typedef __attribute__((ext_vector_type(8))) short bf16x8;
typedef __attribute__((ext_vector_type(4))) float f32x4;

typedef const __attribute__((address_space(1))) u32 glb_u32;
typedef __attribute__((address_space(3))) u32 lds_u32;

__device__ __forceinline__ u16 f32_to_bf16_rtne(float f) {
  u32 u = __float_as_uint(f);
  u += 0x7FFFu + ((u >> 16) & 1u);
  return (u16)(u >> 16);
}

// ---------------- kernel 1: f32 -> bf16 convert ----------------
__global__ __launch_bounds__(256) void convert_kernel(const float* __restrict__ P,
                                                      u16* __restrict__ Pb) {
  int i = blockIdx.x * 256 + threadIdx.x;
  float4 v = reinterpret_cast<const float4*>(P)[i];
  uint2 o;
  o.x = (unsigned)f32_to_bf16_rtne(v.x) | ((unsigned)f32_to_bf16_rtne(v.y) << 16);
  o.y = (unsigned)f32_to_bf16_rtne(v.z) | ((unsigned)f32_to_bf16_rtne(v.w) << 16);
  reinterpret_cast<uint2*>(Pb)[i] = o;
}

// ---------------- kernel 2: barrier-free wave-private fused sim + min/max ----
// Each wave: 64 rows (A in regs, reuse-4) x private 128-col strip, processed as
// 8 tiles of 16 cols. Private 3-deep LDS ring (3 x 4KB), global_load_lds +
// wave-private counted vmcnt FIFO. NO __syncthreads anywhere.
// Swizzle (validated r2-r6): LDS_off(c,o) = c*256 + (o ^ ((c&15)<<4)),
// inverse applied on the global source, same XOR on the ds_read side.
template <bool DIAG>
__device__ __forceinline__ void waveBody(const char* __restrict__ pbb,
                                         const int* __restrict__ y,
                                         float* __restrict__ pmin,
                                         float* __restrict__ pmax,
                                         char* ldsW, int R0, int W0, int slot,
                                         int lane, int c15, int g) {
  // ---- prologue global loads (all retired by the first vmcnt(4)) ----
  const int yv_lo = y[W0 + lane];        // class of col W0+lane  (tiles 0-3)
  const int yv_hi = y[W0 + 64 + lane];   // tiles 4-7

  bf16x8 afrag[4][4];                    // 4 rowgroups x 16 rows, K=128
#pragma unroll
  for (int rg = 0; rg < 4; ++rg) {
    const char* ap = pbb + (size_t)(R0 + rg * 16 + c15) * 256 + g * 16;
#pragma unroll
    for (int kk = 0; kk < 4; ++kk)
      afrag[rg][kk] = *reinterpret_cast<const bf16x8*>(ap + kk * 64);
  }
  int yrow[4][4];
#pragma unroll
  for (int rg = 0; rg < 4; ++rg)
#pragma unroll
    for (int r = 0; r < 4; ++r)
      yrow[rg][r] = y[R0 + rg * 16 + g * 4 + r];

  float rmin[4][4], rmax[4][4];
#pragma unroll
  for (int rg = 0; rg < 4; ++rg)
#pragma unroll
    for (int r = 0; r < 4; ++r) { rmin[rg][r] = FLT_MAX; rmax[rg][r] = -FLT_MAX; }

  // stage tile t (16 cols x 256B = 4KB) into ring slot t%3: exactly 4 vm ops
  auto STAGE = [&](int t) {
    const char* gb = pbb + (size_t)(W0 + t * 16) * 256;
    char* base = ldsW + (t % 3) * 4096;
#pragma unroll
    for (int j = 0; j < 4; ++j) {
      const int L = (j * 64 + lane) * 16;              // linear LDS byte
      const int c = L >> 8, o = L & 255;
      const int src = c * 256 + (o ^ ((c & 15) << 4)); // inverse-swizzled src
      __builtin_amdgcn_global_load_lds((glb_u32*)(gb + src),
                                       (lds_u32*)(base + j * 1024), 16, 0, 0);
    }
  };

  __builtin_amdgcn_sched_barrier(0);   // pin vm order: prologue before S0/S1
  STAGE(0);
  STAGE(1);
  __builtin_amdgcn_sched_barrier(0);

#pragma unroll
  for (int p = 0; p < 4; ++p) {        // fully unrolled: %3 and vmcnt are static
    const int a = 2 * p, b = 2 * p + 1;

    // retire S(a) (and, at p=0, all prologue loads); S(a+1) stays in flight
    asm volatile("s_waitcnt vmcnt(4)" ::: "memory");

    bf16x8 bfA[4];
    const char* BbA = ldsW + (a % 3) * 4096;
#pragma unroll
    for (int kk = 0; kk < 4; ++kk)
      bfA[kk] = *reinterpret_cast<const bf16x8*>(
          BbA + c15 * 256 + (((g * 16) | (kk * 64)) ^ (c15 << 4)));
    if (a + 2 < NTILES) STAGE(a + 2);  // ring slot (a+2)%3: not in use

    f32x4 accA[4];
#pragma unroll
    for (int rg = 0; rg < 4; ++rg) accA[rg] = (f32x4){0.f, 0.f, 0.f, 0.f};
    __builtin_amdgcn_s_setprio(1);
#pragma unroll
    for (int kk = 0; kk < 4; ++kk)
#pragma unroll
      for (int rg = 0; rg < 4; ++rg)
        accA[rg] = __builtin_amdgcn_mfma_f32_16x16x32_bf16(afrag[rg][kk], bfA[kk],
                                                           accA[rg], 0, 0, 0);
    __builtin_amdgcn_s_setprio(0);

    // S(b+2) reuses ring slot a%3 — safe only after bfA reads completed, which
    // the compiler's lgkmcnt before the MFMA block guarantees; pin the order.
    __builtin_amdgcn_sched_barrier(0);
    if (b + 2 < NTILES) STAGE(b + 2);

    // retire S(b): leaves S(a+2),S(b+2) (8 ops) in flight; last pair drains all
    if (p < 3) asm volatile("s_waitcnt vmcnt(8)" ::: "memory");
    else       asm volatile("s_waitcnt vmcnt(0)" ::: "memory");

    bf16x8 bfB[4];
    const char* BbB = ldsW + (b % 3) * 4096;
#pragma unroll
    for (int kk = 0; kk < 4; ++kk)
      bfB[kk] = *reinterpret_cast<const bf16x8*>(
          BbB + c15 * 256 + (((g * 16) | (kk * 64)) ^ (c15 << 4)));

    f32x4 accB[4];
#pragma unroll
    for (int rg = 0; rg < 4; ++rg) accB[rg] = (f32x4){0.f, 0.f, 0.f, 0.f};
    __builtin_amdgcn_s_setprio(1);
#pragma unroll
    for (int kk = 0; kk < 4; ++kk)
#pragma unroll
      for (int rg = 0; rg < 4; ++rg)
        accB[rg] = __builtin_amdgcn_mfma_f32_16x16x32_bf16(afrag[rg][kk], bfB[kk],
                                                           accB[rg], 0, 0, 0);
    __builtin_amdgcn_s_setprio(0);

    // paired epilogue: 2 cols per row -> min3/max3; 4 VALU ops per element
    const int ycolA = __shfl((a < 4) ? yv_lo : yv_hi, c15 + ((a & 3) << 4), 64);
    const int ycolB = __shfl((b < 4) ? yv_lo : yv_hi, c15 + ((b & 3) << 4), 64);
    const int colgA = W0 + a * 16 + c15;
    const int colgB = W0 + b * 16 + c15;
#pragma unroll
    for (int rg = 0; rg < 4; ++rg)
#pragma unroll
      for (int r = 0; r < 4; ++r) {
        const float vA = accA[rg][r], vB = accB[rg][r];
        const bool sA = (ycolA == yrow[rg][r]);
        const bool sB = (ycolB == yrow[rg][r]);
        bool mA = sA, mB = sB;
        if (DIAG) {
          const int rowg = R0 + rg * 16 + g * 4 + r;
          mA = sA && (colgA != rowg);
          mB = sB && (colgB != rowg);
        }
        const float cnA = mA ? vA : FLT_MAX;
        const float cnB = mB ? vB : FLT_MAX;
        const float cxA = sA ? -FLT_MAX : vA;
        const float cxB = sB ? -FLT_MAX : vB;
        rmin[rg][r] = fminf(fminf(rmin[rg][r], cnA), cnB);   // v_min3_f32
        rmax[rg][r] = fmaxf(fmaxf(rmax[rg][r], cxA), cxB);   // v_max3_f32
      }
  }

  // butterfly over the 16 col-lanes (bits 0-3; stays within g-group)
#pragma unroll
  for (int off = 1; off < 16; off <<= 1)
#pragma unroll
    for (int rg = 0; rg < 4; ++rg)
#pragma unroll
      for (int r = 0; r < 4; ++r) {
        rmin[rg][r] = fminf(rmin[rg][r], __shfl_xor(rmin[rg][r], off, 64));
        rmax[rg][r] = fmaxf(rmax[rg][r], __shfl_xor(rmax[rg][r], off, 64));
      }

  if (c15 == 0) {
#pragma unroll
    for (int rg = 0; rg < 4; ++rg)
#pragma unroll
      for (int r = 0; r < 4; ++r) {
        const int row = R0 + rg * 16 + g * 4 + r;
        pmin[(size_t)slot * N + row] = rmin[rg][r];
        pmax[(size_t)slot * N + row] = rmax[rg][r];
      }
  }
}

__global__ __launch_bounds__(256) void margin_main(const u16* __restrict__ Pb,
                                                   const int* __restrict__ y,
                                                   float* __restrict__ pmin,
                                                   float* __restrict__ pmax) {
  __shared__ __align__(16) char ldsAll[4][3][4096];  // 48 KB: per-wave 3-deep ring
  const int tid  = threadIdx.x;
  const int w    = tid >> 6;
  const int lane = tid & 63;
  const int c15  = lane & 15;
  const int g    = lane >> 4;

  const int R0 = blockIdx.x * BM;
  const int W0 = blockIdx.y * (4 * WCOLS) + w * WCOLS;
  const int slot = blockIdx.y * 4 + w;
  char* ldsW = &ldsAll[w][0][0];

  const bool diag = (W0 < R0 + BM) && (W0 + WCOLS > R0);
  if (diag)
    waveBody<true >((const char*)Pb, y, pmin, pmax, ldsW, R0, W0, slot, lane, c15, g);
  else
    waveBody<false>((const char*)Pb, y, pmin, pmax, ldsW, R0, W0, slot, lane, c15, g);
}

// ---------------- kernel 3: combine partials, hinge, block sums ----------------
__global__ __launch_bounds__(256) void loss_kernel(const float* __restrict__ pmin,
                                                   const float* __restrict__ pmax,
                                                   float* __restrict__ blockSums) {
  const int row = blockIdx.x * 256 + threadIdx.x;
  float mn = FLT_MAX, mx = -FLT_MAX;
#pragma unroll 8
  for (int s = 0; s < NPART; ++s) {            // slot-major: coalesced
    mn = fminf(mn, pmin[(size_t)s * N + row]);
    mx = fmaxf(mx, pmax[(size_t)s * N + row]);
  }
  if (mn == FLT_MAX)  mn = 0.f;
  if (mx == -FLT_MAX) mx = 0.f;
  float loss = fmaxf(0.f, mn + mx + 1.0f);     // TAU = 1.0

#pragma unroll
  for (int off = 32; off >= 1; off >>= 1)
    loss += __shfl_down(loss, off, 64);
  __shared__ float wsum[4];
  if ((threadIdx.x & 63) == 0) wsum[threadIdx.x >> 6] = loss;
  __syncthreads();
  if (threadIdx.x == 0)
    blockSums[blockIdx.x] = wsum[0] + wsum[1] + wsum[2] + wsum[3];
}

// ---------------- kernel 4: final mean ----------------
__global__ __launch_bounds__(64) void finalize_kernel(const float* __restrict__ blockSums,
                                                      float* __restrict__ out) {
  float v = (threadIdx.x < LOSS_BLOCKS) ? blockSums[threadIdx.x] : 0.f;
#pragma unroll
  for (int off = 32; off >= 1; off >>= 1)
    v += __shfl_down(v, off, 64);
  if (threadIdx.x == 0) out[0] = v / (float)N;
}

extern "C" void kernel_launch(void* const* d_in, const int* in_sizes, int n_in,
                              void* d_out, int out_size, void* d_ws, size_t ws_size,
                              hipStream_t stream) {
  const float* P = (const float*)d_in[0];
  const int*   y = (const int*)d_in[1];
  float* out = (float*)d_out;

  // ws: Pb (2MB) | pmin (2MB) | pmax (2MB) | blockSums
  u16* Pb          = (u16*)d_ws;
  float* pmin      = (float*)((char*)d_ws + (size_t)N * D * sizeof(u16));
  float* pmax      = pmin + (size_t)N * NPART;
  float* blockSums = pmax + (size_t)N * NPART;

  convert_kernel<<<dim3(N * D / 4 / 256), 256, 0, stream>>>(P, Pb);
  margin_main<<<dim3(N / BM, GY), 256, 0, stream>>>(Pb, y, pmin, pmax);
  loss_kernel<<<dim3(LOSS_BLOCKS), 256, 0, stream>>>(pmin, pmax, blockSums);
  finalize_kernel<<<1, 64, 0, stream>>>(blockSums, out);
}

// Round 8
// 46.500 us; speedup vs baseline: 4.6045x; 1.7525x over previous
//
#include <hip/hip_runtime.h>
#include <hip/hip_bf16.h>
#include <float.h>

#define N 8192
#define D 128
#define NCLS 100
#define BM 256                       // rows per block: 4 waves x 64
#define BN 64                        // cols per LDS tile
#define GY 16                        // col-chunks (grid.y)
#define COLS_PER_BLOCK (N / GY)      // 512
#define TILES (COLS_PER_BLOCK / BN)  // 8
#define NPART GY
#define LOSS_BLOCKS (N / 256)        // 32

typedef unsigned short u16;
typedef unsigned int u32;
typedef __attribute__((ext_vector_type(8))) short bf16x8;
typedef __attribute__((ext_vector_type(4))) float f32x4;

typedef const __attribute__((address_space(1))) u32 glb_u32;
typedef __attribute__((address_space(3))) u32 lds_u32;

__device__ __forceinline__ u32 pack_bf16x2(float a, float b) {
  u32 ua = __float_as_uint(a); ua += 0x7FFFu + ((ua >> 16) & 1u);
  u32 ub = __float_as_uint(b); ub += 0x7FFFu + ((ub >> 16) & 1u);
  return (ua >> 16) | (ub & 0xFFFF0000u);
}

// ---- kernel 1: stable counting-sort scatter (one block per class) ----------
// Deterministic: row order preserved within class. Writes perm, yp (class of
// permuted row), rs/re (class range [start,end) per permuted row).
__global__ __launch_bounds__(256) void sort_kernel(const int* __restrict__ y,
                                                   int* __restrict__ perm,
                                                   int* __restrict__ yp,
                                                   int* __restrict__ rs,
                                                   int* __restrict__ re) {
  const int c    = blockIdx.x;           // class id
  const int ww   = threadIdx.x >> 6;     // wave 0..3, owns rows [ww*2048, +2048)
  const int lane = threadIdx.x & 63;
  const int base0 = ww * (N / 4);

  int lt = 0, eq = 0;
#pragma unroll 2
  for (int i = 0; i < N / 4; i += 256) { // 4 independent loads per iter (ILP)
    int v0 = y[base0 + i + lane];
    int v1 = y[base0 + i + 64 + lane];
    int v2 = y[base0 + i + 128 + lane];
    int v3 = y[base0 + i + 192 + lane];
    lt += (v0 < c) + (v1 < c) + (v2 < c) + (v3 < c);
    eq += (v0 == c) + (v1 == c) + (v2 == c) + (v3 == c);
  }
#pragma unroll
  for (int off = 32; off >= 1; off >>= 1) {
    lt += __shfl_down(lt, off, 64);
    eq += __shfl_down(eq, off, 64);
  }
  __shared__ int ltW[4], eqW[4];
  if (lane == 0) { ltW[ww] = lt; eqW[ww] = eq; }
  __syncthreads();
  const int start = ltW[0] + ltW[1] + ltW[2] + ltW[3];
  const int cnt   = eqW[0] + eqW[1] + eqW[2] + eqW[3];
  const int end   = start + cnt;
  int run = start;
  for (int w2 = 0; w2 < ww; ++w2) run += eqW[w2];

  const unsigned long long below = (lane == 0) ? 0ull : ((1ull << lane) - 1ull);
#pragma unroll 2
  for (int i = 0; i < N / 4; i += 128) {
    int v0 = y[base0 + i + lane];
    int v1 = y[base0 + i + 64 + lane];
    unsigned long long m0 = __ballot(v0 == c);
    unsigned long long m1 = __ballot(v1 == c);
    if (v0 == c) {
      int pos = run + __popcll(m0 & below);
      perm[pos] = base0 + i + lane; yp[pos] = c; rs[pos] = start; re[pos] = end;
    }
    run += __popcll(m0);
    if (v1 == c) {
      int pos = run + __popcll(m1 & below);
      perm[pos] = base0 + i + 64 + lane; yp[pos] = c; rs[pos] = start; re[pos] = end;
    }
    run += __popcll(m1);
  }
}

// ---- kernel 2: gather permuted rows + f32->bf16 convert ---------------------
__global__ __launch_bounds__(256) void gather_kernel(const float* __restrict__ P,
                                                     const int* __restrict__ perm,
                                                     u16* __restrict__ Pp) {
  const int rloc = threadIdx.x >> 4;              // 16 rows per block
  const int t16  = threadIdx.x & 15;              // 16 threads per row
  const int k    = blockIdx.x * 16 + rloc;        // permuted row
  const int src  = perm[k];
  const float4* s = reinterpret_cast<const float4*>(P + (size_t)src * D) + t16 * 2;
  float4 v0 = s[0], v1 = s[1];
  uint4 o;
  o.x = pack_bf16x2(v0.x, v0.y);
  o.y = pack_bf16x2(v0.z, v0.w);
  o.z = pack_bf16x2(v1.x, v1.y);
  o.w = pack_bf16x2(v1.z, v1.w);
  reinterpret_cast<uint4*>(Pp + (size_t)k * D)[t16] = o;
}

// ---- kernel 3: fused permuted-Gram + zone-gated min/max ---------------------
// r3-proven skeleton: 4 waves x 64 rows (reuse-4), 3-deep ring, counted vmcnt,
// per-tile barrier. Swizzle (validated r2-r7): LDS_off(c,o)=c*256+(o^((c&15)<<4)),
// inverse on the global source, same XOR on the ds_read side (rule 21).
// Epilogue: wave-uniform zone test -> fast path (1 fmax/elem) or masked path.
__global__ __launch_bounds__(256) void margin_main(const u16* __restrict__ Pp,
                                                   const int* __restrict__ yp,
                                                   const int* __restrict__ rs,
                                                   const int* __restrict__ re,
                                                   float* __restrict__ pmin,
                                                   float* __restrict__ pmax) {
  __shared__ __align__(16) char ldsB[3][BN * 256];   // 48 KB
  __shared__ int ldsY[COLS_PER_BLOCK];               // 2 KB

  const int tid  = threadIdx.x;
  const int w    = tid >> 6;
  const int lane = tid & 63;
  const int c15  = lane & 15;
  const int g    = lane >> 4;

  const int R0 = blockIdx.x * BM;
  const int C0 = blockIdx.y * COLS_PER_BLOCK;
  const char* pbb = (const char*)Pp;

  // stage yp slice: wave w stages ints [w*128, +128)  (2 vm ops)
  {
    const int* gy = yp + C0 + w * 128 + lane;
    lds_u32* dst = (lds_u32*)(ldsY + w * 128);
    __builtin_amdgcn_global_load_lds((glb_u32*)gy,        dst,      4, 0, 0);
    __builtin_amdgcn_global_load_lds((glb_u32*)(gy + 64), dst + 64, 4, 0, 0);
  }

  auto STAGE = [&](int buf, int t) {      // 16KB tile, 4 glds x 1KB per wave
    const char* gb = pbb + (size_t)(C0 + t * BN) * 256;
    char* base = &ldsB[buf][0];
#pragma unroll
    for (int j = 0; j < 4; ++j) {
      const int L = ((w * 4 + j) * 64 + lane) * 16;
      const int c = L >> 8, o = L & 255;
      const int src = c * 256 + (o ^ ((c & 15) << 4));
      __builtin_amdgcn_global_load_lds((glb_u32*)(gb + src),
                                       (lds_u32*)(base + (w * 4 + j) * 1024), 16, 0, 0);
    }
  };

  STAGE(0, 0);
  STAGE(1, 1);

  const int R0w = R0 + w * 64;
  const int stripLo = __builtin_amdgcn_readfirstlane(rs[R0w]);       // zone start
  const int stripHi = __builtin_amdgcn_readfirstlane(re[R0w + 63]);  // zone end

  bf16x8 afrag[4][4];                    // 4 rowgroups x 16 rows, K=128
#pragma unroll
  for (int rg = 0; rg < 4; ++rg) {
    const char* ap = pbb + (size_t)(R0w + rg * 16 + c15) * 256 + g * 16;
#pragma unroll
    for (int kk = 0; kk < 4; ++kk)
      afrag[rg][kk] = *reinterpret_cast<const bf16x8*>(ap + kk * 64);
  }
  int yrow[4][4];
#pragma unroll
  for (int rg = 0; rg < 4; ++rg)
#pragma unroll
    for (int r = 0; r < 4; ++r)
      yrow[rg][r] = yp[R0w + rg * 16 + g * 4 + r];

  float rmin[4][4], rmax[4][4];
#pragma unroll
  for (int rg = 0; rg < 4; ++rg)
#pragma unroll
    for (int r = 0; r < 4; ++r) { rmin[rg][r] = FLT_MAX; rmax[rg][r] = -FLT_MAX; }

#pragma unroll 1
  for (int t = 0; t < TILES; ++t) {
    // counted vmcnt: stage(t) drained; stage(t+1)'s 4 loads stay in flight
    if (t + 1 < TILES) asm volatile("s_waitcnt vmcnt(4)" ::: "memory");
    else               asm volatile("s_waitcnt vmcnt(0)" ::: "memory");
    __builtin_amdgcn_s_barrier();        // all waves' stage(t) landed;
                                         // buf[(t+2)%3] free (read in t-1)
    if (t + 2 < TILES) STAGE((t + 2) % 3, t + 2);

    const char* Bb = &ldsB[t % 3][0];
#pragma unroll
    for (int s = 0; s < 4; ++s) {
      const int c = s * 16 + c15;
      bf16x8 bf[4];
#pragma unroll
      for (int kk = 0; kk < 4; ++kk) {
        const int off = c * 256 + (((g * 16) | (kk * 64)) ^ (c15 << 4));
        bf[kk] = *reinterpret_cast<const bf16x8*>(Bb + off);
      }
      f32x4 acc[4];
#pragma unroll
      for (int rg = 0; rg < 4; ++rg) acc[rg] = (f32x4){0.f, 0.f, 0.f, 0.f};
      __builtin_amdgcn_s_setprio(1);
#pragma unroll
      for (int kk = 0; kk < 4; ++kk)
#pragma unroll
        for (int rg = 0; rg < 4; ++rg)
          acc[rg] = __builtin_amdgcn_mfma_f32_16x16x32_bf16(afrag[rg][kk], bf[kk],
                                                            acc[rg], 0, 0, 0);
      __builtin_amdgcn_s_setprio(0);

      const int colT = C0 + t * BN + s * 16;         // wave-uniform
      if (colT + 16 <= stripLo || colT >= stripHi) {
        // fast path: every col diff-class for every row of this strip
#pragma unroll
        for (int rg = 0; rg < 4; ++rg)
#pragma unroll
          for (int r = 0; r < 4; ++r)
            rmax[rg][r] = fmaxf(rmax[rg][r], acc[rg][r]);
      } else {
        // slow path: per-element class mask + self-exclusion (r3-proven)
        const int ycol = ldsY[t * BN + s * 16 + c15];
        const int colg = colT + c15;
#pragma unroll
        for (int rg = 0; rg < 4; ++rg)
#pragma unroll
          for (int r = 0; r < 4; ++r) {
            const float v = acc[rg][r];
            const bool same = (ycol == yrow[rg][r]);
            const bool okmin = same && (colg != R0w + rg * 16 + g * 4 + r);
            rmin[rg][r] = fminf(rmin[rg][r], okmin ? v : FLT_MAX);
            rmax[rg][r] = fmaxf(rmax[rg][r], same ? -FLT_MAX : v);
          }
      }
    }
  }

  // butterfly over the 16 col-lanes (bits 0-3; stays within g-group)
#pragma unroll
  for (int off = 1; off < 16; off <<= 1)
#pragma unroll
    for (int rg = 0; rg < 4; ++rg)
#pragma unroll
      for (int r = 0; r < 4; ++r) {
        rmin[rg][r] = fminf(rmin[rg][r], __shfl_xor(rmin[rg][r], off, 64));
        rmax[rg][r] = fmaxf(rmax[rg][r], __shfl_xor(rmax[rg][r], off, 64));
      }

  if (c15 == 0) {
#pragma unroll
    for (int rg = 0; rg < 4; ++rg)
#pragma unroll
      for (int r = 0; r < 4; ++r) {
        const int row = R0w + rg * 16 + g * 4 + r;     // permuted row index
        pmin[(size_t)blockIdx.y * N + row] = rmin[rg][r];
        pmax[(size_t)blockIdx.y * N + row] = rmax[rg][r];
      }
  }
}

// ---- kernel 4: combine partials, hinge, block sums --------------------------
// Rows are permuted rows; mean over rows is permutation-invariant.
__global__ __launch_bounds__(256) void loss_kernel(const float* __restrict__ pmin,
                                                   const float* __restrict__ pmax,
                                                   float* __restrict__ blockSums) {
  const int row = blockIdx.x * 256 + threadIdx.x;
  float mn = FLT_MAX, mx = -FLT_MAX;
#pragma unroll
  for (int s = 0; s < NPART; ++s) {
    mn = fminf(mn, pmin[(size_t)s * N + row]);
    mx = fmaxf(mx, pmax[(size_t)s * N + row]);
  }
  if (mn == FLT_MAX)  mn = 0.f;   // no same-class partner
  if (mx == -FLT_MAX) mx = 0.f;   // no diff-class partner
  float loss = fmaxf(0.f, mn + mx + 1.0f);     // TAU = 1.0

#pragma unroll
  for (int off = 32; off >= 1; off >>= 1)
    loss += __shfl_down(loss, off, 64);
  __shared__ float wsum[4];
  if ((threadIdx.x & 63) == 0) wsum[threadIdx.x >> 6] = loss;
  __syncthreads();
  if (threadIdx.x == 0)
    blockSums[blockIdx.x] = wsum[0] + wsum[1] + wsum[2] + wsum[3];
}

// ---- kernel 5: final mean ---------------------------------------------------
__global__ __launch_bounds__(64) void finalize_kernel(const float* __restrict__ blockSums,
                                                      float* __restrict__ out) {
  float v = (threadIdx.x < LOSS_BLOCKS) ? blockSums[threadIdx.x] : 0.f;
#pragma unroll
  for (int off = 32; off >= 1; off >>= 1)
    v += __shfl_down(v, off, 64);
  if (threadIdx.x == 0) out[0] = v / (float)N;
}

extern "C" void kernel_launch(void* const* d_in, const int* in_sizes, int n_in,
                              void* d_out, int out_size, void* d_ws, size_t ws_size,
                              hipStream_t stream) {
  const float* P = (const float*)d_in[0];
  const int*   y = (const int*)d_in[1];
  float* out = (float*)d_out;

  // ws: Pp (2MB) | perm|yp|rs|re (4x32KB) | pmin (512KB) | pmax (512KB) | sums
  u16* Pp   = (u16*)d_ws;
  int* perm = (int*)((char*)d_ws + (size_t)N * D * sizeof(u16));
  int* yp   = perm + N;
  int* rs   = yp + N;
  int* re   = rs + N;
  float* pmin = (float*)(re + N);
  float* pmax = pmin + (size_t)N * NPART;
  float* blockSums = pmax + (size_t)N * NPART;

  sort_kernel<<<dim3(NCLS), 256, 0, stream>>>(y, perm, yp, rs, re);
  gather_kernel<<<dim3(N / 16), 256, 0, stream>>>(P, perm, Pp);
  margin_main<<<dim3(N / BM, GY), 256, 0, stream>>>(Pp, yp, rs, re, pmin, pmax);
  loss_kernel<<<dim3(LOSS_BLOCKS), 256, 0, stream>>>(pmin, pmax, blockSums);
  finalize_kernel<<<1, 64, 0, stream>>>(blockSums, out);
}

// Round 9
// 42.788 us; speedup vs baseline: 5.0040x; 1.0868x over previous
//
#include <hip/hip_runtime.h>
#include <hip/hip_bf16.h>
#include <float.h>

#define N 8192
#define D 128
#define NCLS 100
#define BM 256                       // rows per block: 8 waves x 32
#define BN 64                        // cols per LDS tile
#define GY 16                        // col-chunks (grid.y)
#define COLS_PER_BLOCK (N / GY)      // 512
#define TILES (COLS_PER_BLOCK / BN)  // 8
#define NPART GY
#define LOSS_BLOCKS (N / 256)        // 32

typedef unsigned short u16;
typedef unsigned int u32;
typedef __attribute__((ext_vector_type(8))) short bf16x8;
typedef __attribute__((ext_vector_type(4))) float f32x4;

typedef const __attribute__((address_space(1))) u32 glb_u32;
typedef __attribute__((address_space(3))) u32 lds_u32;

__device__ __forceinline__ u32 pack_bf16x2(float a, float b) {
  u32 ua = __float_as_uint(a); ua += 0x7FFFu + ((ua >> 16) & 1u);
  u32 ub = __float_as_uint(b); ub += 0x7FFFu + ((ub >> 16) & 1u);
  return (ua >> 16) | (ub & 0xFFFF0000u);
}

// ---- kernel 1: stable counting-sort scatter (one block per class) ----------
__global__ __launch_bounds__(256) void sort_kernel(const int* __restrict__ y,
                                                   int* __restrict__ perm,
                                                   int* __restrict__ yp,
                                                   int* __restrict__ rs,
                                                   int* __restrict__ re) {
  const int c    = blockIdx.x;           // class id
  const int ww   = threadIdx.x >> 6;     // wave 0..3, owns rows [ww*2048, +2048)
  const int lane = threadIdx.x & 63;
  const int base0 = ww * (N / 4);

  int lt = 0, eq = 0;
#pragma unroll 2
  for (int i = 0; i < N / 4; i += 256) {
    int v0 = y[base0 + i + lane];
    int v1 = y[base0 + i + 64 + lane];
    int v2 = y[base0 + i + 128 + lane];
    int v3 = y[base0 + i + 192 + lane];
    lt += (v0 < c) + (v1 < c) + (v2 < c) + (v3 < c);
    eq += (v0 == c) + (v1 == c) + (v2 == c) + (v3 == c);
  }
#pragma unroll
  for (int off = 32; off >= 1; off >>= 1) {
    lt += __shfl_down(lt, off, 64);
    eq += __shfl_down(eq, off, 64);
  }
  __shared__ int ltW[4], eqW[4];
  if (lane == 0) { ltW[ww] = lt; eqW[ww] = eq; }
  __syncthreads();
  const int start = ltW[0] + ltW[1] + ltW[2] + ltW[3];
  const int cnt   = eqW[0] + eqW[1] + eqW[2] + eqW[3];
  const int end   = start + cnt;
  int run = start;
  for (int w2 = 0; w2 < ww; ++w2) run += eqW[w2];

  const unsigned long long below = (lane == 0) ? 0ull : ((1ull << lane) - 1ull);
#pragma unroll 2
  for (int i = 0; i < N / 4; i += 128) {
    int v0 = y[base0 + i + lane];
    int v1 = y[base0 + i + 64 + lane];
    unsigned long long m0 = __ballot(v0 == c);
    unsigned long long m1 = __ballot(v1 == c);
    if (v0 == c) {
      int pos = run + __popcll(m0 & below);
      perm[pos] = base0 + i + lane; yp[pos] = c; rs[pos] = start; re[pos] = end;
    }
    run += __popcll(m0);
    if (v1 == c) {
      int pos = run + __popcll(m1 & below);
      perm[pos] = base0 + i + 64 + lane; yp[pos] = c; rs[pos] = start; re[pos] = end;
    }
    run += __popcll(m1);
  }
}

// ---- kernel 2: gather permuted rows + f32->bf16 convert ---------------------
__global__ __launch_bounds__(256) void gather_kernel(const float* __restrict__ P,
                                                     const int* __restrict__ perm,
                                                     u16* __restrict__ Pp) {
  const int rloc = threadIdx.x >> 4;
  const int t16  = threadIdx.x & 15;
  const int k    = blockIdx.x * 16 + rloc;
  const int src  = perm[k];
  const float4* s = reinterpret_cast<const float4*>(P + (size_t)src * D) + t16 * 2;
  float4 v0 = s[0], v1 = s[1];
  uint4 o;
  o.x = pack_bf16x2(v0.x, v0.y);
  o.y = pack_bf16x2(v0.z, v0.w);
  o.z = pack_bf16x2(v1.x, v1.y);
  o.w = pack_bf16x2(v1.z, v1.w);
  reinterpret_cast<uint4*>(Pp + (size_t)k * D)[t16] = o;
}

// ---- kernel 3: phase-structured fused permuted-Gram + zone-gated min/max ----
// 8 waves x 32 rows (reuse-2), 3-deep ring, counted vmcnt(2) per tile, and
// per-16-col-subtile phases: {ds_read (+stage in ph0) | bar | setprio MFMA |
// bar | epilogue}  (T3+T4+T5, m201 pattern adapted to streamed columns).
// Swizzle (validated r2-r8): LDS_off(c,o)=c*256+(o^((c&15)<<4)); inverse on
// the global source, same XOR on the ds_read side (rule 21).
__global__ __launch_bounds__(512) void margin_main(const u16* __restrict__ Pp,
                                                   const int* __restrict__ yp,
                                                   const int* __restrict__ rs,
                                                   const int* __restrict__ re,
                                                   float* __restrict__ pmin,
                                                   float* __restrict__ pmax) {
  __shared__ __align__(16) char ldsB[3][BN * 256];   // 48 KB
  __shared__ int ldsY[COLS_PER_BLOCK];               // 2 KB

  const int tid  = threadIdx.x;
  const int w    = tid >> 6;         // 0..7
  const int lane = tid & 63;
  const int c15  = lane & 15;
  const int g    = lane >> 4;

  const int R0 = blockIdx.x * BM;
  const int C0 = blockIdx.y * COLS_PER_BLOCK;
  const char* pbb = (const char*)Pp;
  const int R0w = R0 + w * 32;

  // ---- prologue normal loads (pinned BEFORE the stage glds for vmcnt math) --
  bf16x8 afrag[2][4];                  // 2 rowgroups x 16 rows, K=128
#pragma unroll
  for (int rg = 0; rg < 2; ++rg) {
    const char* ap = pbb + (size_t)(R0w + rg * 16 + c15) * 256 + g * 16;
#pragma unroll
    for (int kk = 0; kk < 4; ++kk)
      afrag[rg][kk] = *reinterpret_cast<const bf16x8*>(ap + kk * 64);
  }
  int yrow[2][4];
#pragma unroll
  for (int rg = 0; rg < 2; ++rg)
#pragma unroll
    for (int r = 0; r < 4; ++r)
      yrow[rg][r] = yp[R0w + rg * 16 + g * 4 + r];
  const int stripLo = __builtin_amdgcn_readfirstlane(rs[R0w]);
  const int stripHi = __builtin_amdgcn_readfirstlane(re[R0w + 31]);

  auto STAGE = [&](int buf, int t) {   // 16KB tile: 2 glds x 1KB per wave
    const char* gb = pbb + (size_t)(C0 + t * BN) * 256;
    char* base = &ldsB[buf][0];
#pragma unroll
    for (int j = 0; j < 2; ++j) {
      const int L = ((w * 2 + j) * 64 + lane) * 16;
      const int c = L >> 8, o = L & 255;
      const int src = c * 256 + (o ^ ((c & 15) << 4));
      __builtin_amdgcn_global_load_lds((glb_u32*)(gb + src),
                                       (lds_u32*)(base + (w * 2 + j) * 1024), 16, 0, 0);
    }
  };

  __builtin_amdgcn_sched_barrier(0);   // prologue loads issue first
  // y slice: wave w stages 64 ints (1 gld)
  __builtin_amdgcn_global_load_lds((glb_u32*)(yp + C0 + w * 64 + lane),
                                   (lds_u32*)(ldsY + w * 64), 4, 0, 0);
  STAGE(0, 0);
  STAGE(1, 1);
  __builtin_amdgcn_sched_barrier(0);   // glds last: vmcnt(2) => S1 in flight

  float rmin[2][4], rmax[2][4];
#pragma unroll
  for (int rg = 0; rg < 2; ++rg)
#pragma unroll
    for (int r = 0; r < 4; ++r) { rmin[rg][r] = FLT_MAX; rmax[rg][r] = -FLT_MAX; }

#pragma unroll 1
  for (int t = 0; t < TILES; ++t) {
    // counted vmcnt: stage(t) retired (FIFO); stage(t+1)'s 2 stay in flight
    if (t + 1 < TILES) asm volatile("s_waitcnt vmcnt(2)" ::: "memory");
    else               asm volatile("s_waitcnt vmcnt(0)" ::: "memory");
    __builtin_amdgcn_s_barrier();      // buf[t%3] visible to all waves;
                                       // all t-1 reads retired => buf[(t+2)%3] free
    const char* Bb = &ldsB[t % 3][0];
#pragma unroll
    for (int s = 0; s < 4; ++s) {      // ---- 4 phases per tile ----
      const int c = s * 16 + c15;
      bf16x8 bf[4];
#pragma unroll
      for (int kk = 0; kk < 4; ++kk) {
        const int off = c * 256 + (((g * 16) | (kk * 64)) ^ (c15 << 4));
        bf[kk] = *reinterpret_cast<const bf16x8*>(Bb + off);
      }
      if (s == 0 && t + 2 < TILES) STAGE((t + 2) % 3, t + 2);

      __builtin_amdgcn_s_barrier();    // cluster DS reads apart from MFMA

      f32x4 acc0 = {0.f, 0.f, 0.f, 0.f}, acc1 = {0.f, 0.f, 0.f, 0.f};
      __builtin_amdgcn_s_setprio(1);
#pragma unroll
      for (int kk = 0; kk < 4; ++kk) {
        acc0 = __builtin_amdgcn_mfma_f32_16x16x32_bf16(afrag[0][kk], bf[kk], acc0, 0, 0, 0);
        acc1 = __builtin_amdgcn_mfma_f32_16x16x32_bf16(afrag[1][kk], bf[kk], acc1, 0, 0, 0);
      }
      __builtin_amdgcn_s_setprio(0);

      __builtin_amdgcn_s_barrier();    // phase boundary

      const int colT = C0 + t * BN + s * 16;           // wave-uniform
      if (colT + 16 <= stripLo || colT >= stripHi) {
        // fast path: every col diff-class for this strip (1 fmax/elem)
#pragma unroll
        for (int r = 0; r < 4; ++r) {
          rmax[0][r] = fmaxf(rmax[0][r], acc0[r]);
          rmax[1][r] = fmaxf(rmax[1][r], acc1[r]);
        }
      } else {
        // slow path: per-element class mask + self-exclusion
        const int ycol = ldsY[t * BN + s * 16 + c15];
        const int colg = colT + c15;
#pragma unroll
        for (int rg = 0; rg < 2; ++rg)
#pragma unroll
          for (int r = 0; r < 4; ++r) {
            const float v = (rg == 0) ? acc0[r] : acc1[r];
            const bool same = (ycol == yrow[rg][r]);
            const bool okmin = same && (colg != R0w + rg * 16 + g * 4 + r);
            rmin[rg][r] = fminf(rmin[rg][r], okmin ? v : FLT_MAX);
            rmax[rg][r] = fmaxf(rmax[rg][r], same ? -FLT_MAX : v);
          }
      }
    }
  }

  // butterfly over the 16 col-lanes (bits 0-3; stays within g-group)
#pragma unroll
  for (int off = 1; off < 16; off <<= 1)
#pragma unroll
    for (int rg = 0; rg < 2; ++rg)
#pragma unroll
      for (int r = 0; r < 4; ++r) {
        rmin[rg][r] = fminf(rmin[rg][r], __shfl_xor(rmin[rg][r], off, 64));
        rmax[rg][r] = fmaxf(rmax[rg][r], __shfl_xor(rmax[rg][r], off, 64));
      }

  if (c15 == 0) {
#pragma unroll
    for (int rg = 0; rg < 2; ++rg)
#pragma unroll
      for (int r = 0; r < 4; ++r) {
        const int row = R0w + rg * 16 + g * 4 + r;     // permuted row index
        pmin[(size_t)blockIdx.y * N + row] = rmin[rg][r];
        pmax[(size_t)blockIdx.y * N + row] = rmax[rg][r];
      }
  }
}

// ---- kernel 4: combine partials, hinge, block sums --------------------------
__global__ __launch_bounds__(256) void loss_kernel(const float* __restrict__ pmin,
                                                   const float* __restrict__ pmax,
                                                   float* __restrict__ blockSums) {
  const int row = blockIdx.x * 256 + threadIdx.x;
  float mn = FLT_MAX, mx = -FLT_MAX;
#pragma unroll
  for (int s = 0; s < NPART; ++s) {
    mn = fminf(mn, pmin[(size_t)s * N + row]);
    mx = fmaxf(mx, pmax[(size_t)s * N + row]);
  }
  if (mn == FLT_MAX)  mn = 0.f;
  if (mx == -FLT_MAX) mx = 0.f;
  float loss = fmaxf(0.f, mn + mx + 1.0f);     // TAU = 1.0

#pragma unroll
  for (int off = 32; off >= 1; off >>= 1)
    loss += __shfl_down(loss, off, 64);
  __shared__ float wsum[4];
  if ((threadIdx.x & 63) == 0) wsum[threadIdx.x >> 6] = loss;
  __syncthreads();
  if (threadIdx.x == 0)
    blockSums[blockIdx.x] = wsum[0] + wsum[1] + wsum[2] + wsum[3];
}

// ---- kernel 5: final mean ---------------------------------------------------
__global__ __launch_bounds__(64) void finalize_kernel(const float* __restrict__ blockSums,
                                                      float* __restrict__ out) {
  float v = (threadIdx.x < LOSS_BLOCKS) ? blockSums[threadIdx.x] : 0.f;
#pragma unroll
  for (int off = 32; off >= 1; off >>= 1)
    v += __shfl_down(v, off, 64);
  if (threadIdx.x == 0) out[0] = v / (float)N;
}

extern "C" void kernel_launch(void* const* d_in, const int* in_sizes, int n_in,
                              void* d_out, int out_size, void* d_ws, size_t ws_size,
                              hipStream_t stream) {
  const float* P = (const float*)d_in[0];
  const int*   y = (const int*)d_in[1];
  float* out = (float*)d_out;

  // ws: Pp (2MB) | perm|yp|rs|re (4x32KB) | pmin (512KB) | pmax (512KB) | sums
  u16* Pp   = (u16*)d_ws;
  int* perm = (int*)((char*)d_ws + (size_t)N * D * sizeof(u16));
  int* yp   = perm + N;
  int* rs   = yp + N;
  int* re   = rs + N;
  float* pmin = (float*)(re + N);
  float* pmax = pmin + (size_t)N * NPART;
  float* blockSums = pmax + (size_t)N * NPART;

  sort_kernel<<<dim3(NCLS), 256, 0, stream>>>(y, perm, yp, rs, re);
  gather_kernel<<<dim3(N / 16), 256, 0, stream>>>(P, perm, Pp);
  margin_main<<<dim3(N / BM, GY), 512, 0, stream>>>(Pp, yp, rs, re, pmin, pmax);
  loss_kernel<<<dim3(LOSS_BLOCKS), 256, 0, stream>>>(pmin, pmax, blockSums);
  finalize_kernel<<<1, 64, 0, stream>>>(blockSums, out);
}

// Round 10
// 39.330 us; speedup vs baseline: 5.4440x; 1.0879x over previous
//
#include <hip/hip_runtime.h>
#include <hip/hip_bf16.h>
#include <float.h>

#define N 8192
#define D 128
#define BM 256                       // rows per block: 4 waves x 64
#define BN 64                        // cols per LDS tile
#define GY 16                        // col-chunks (grid.y)
#define COLS_PER_BLOCK (N / GY)      // 512
#define TILES (COLS_PER_BLOCK / BN)  // 8
#define NPART GY                     // partial slots per row
#define LOSS_BLOCKS (N / 256)        // 32

typedef unsigned short u16;
typedef unsigned int u32;
typedef __attribute__((ext_vector_type(8))) short bf16x8;
typedef __attribute__((ext_vector_type(4))) float f32x4;

typedef const __attribute__((address_space(1))) u32 glb_u32;
typedef __attribute__((address_space(3))) u32 lds_u32;

__device__ inline u16 f32_to_bf16_rtne(float f) {
  union { float f; unsigned int u; } c; c.f = f;
  unsigned int u = c.u;
  u += 0x7FFFu + ((u >> 16) & 1u);
  return (u16)(u >> 16);
}

// ---------------- kernel 1: f32 -> bf16 convert (+ counter zero) -------------
__global__ __launch_bounds__(256) void convert_kernel(const float* __restrict__ P,
                                                      u16* __restrict__ Pb,
                                                      int* __restrict__ counter) {
  int i = blockIdx.x * 256 + threadIdx.x;
  if (i == 0) counter[0] = 0;                  // re-armed every launch (replay-safe)
  float4 v = reinterpret_cast<const float4*>(P)[i];
  uint2 o;
  o.x = (unsigned)f32_to_bf16_rtne(v.x) | ((unsigned)f32_to_bf16_rtne(v.y) << 16);
  o.y = (unsigned)f32_to_bf16_rtne(v.z) | ((unsigned)f32_to_bf16_rtne(v.w) << 16);
  reinterpret_cast<uint2*>(Pb)[i] = o;
}

// ---------------- kernel 2 body: EXACT r3 margin (best measured) -------------
// 3-deep pipelined fused sim + min/max. 4 waves x 64 rows (reuse-4), counted
// vmcnt, one barrier per tile. Swizzle (validated r2-r9):
// LDS_off(c,o) = c*256 + (o ^ ((c&15)<<4)), inverse applied on the global
// source at stage time, same XOR on the ds_read address (rule 21).
template <bool DIAG>
__device__ __forceinline__ void pipeline(const char* __restrict__ pbb,
                                         const int* __restrict__ y,
                                         float* __restrict__ pmin,
                                         float* __restrict__ pmax,
                                         char* ldsB, int* ldsY,
                                         int R0, int C0, int slot) {
  const int tid  = threadIdx.x;
  const int w    = tid >> 6;
  const int lane = tid & 63;
  const int c15  = lane & 15;
  const int g    = lane >> 4;

  // y for the block's 512 cols (wave w: ints [w*128, +128), 2 glds)
  {
    const int* gy = y + C0 + w * 128 + lane;
    lds_u32* dst = (lds_u32*)(ldsY + w * 128);
    __builtin_amdgcn_global_load_lds((glb_u32*)gy,        dst,      4, 0, 0);
    __builtin_amdgcn_global_load_lds((glb_u32*)(gy + 64), dst + 64, 4, 0, 0);
  }

  // stage tile t into buffer buf: 16KB B, 4 glds x 1KB per wave, uniform count
  auto STAGE = [&](int buf, int t) {
    const char* gb = pbb + (size_t)(C0 + t * BN) * 256;
    char* base = ldsB + buf * (BN * 256);
#pragma unroll
    for (int j = 0; j < 4; ++j) {
      const int L = ((w * 4 + j) * 64 + lane) * 16;    // linear LDS byte
      const int c = L >> 8;
      const int o = L & 255;
      const int src = c * 256 + (o ^ ((c & 15) << 4)); // inverse-swizzled source
      __builtin_amdgcn_global_load_lds((glb_u32*)(gb + src),
                                       (lds_u32*)(base + (w * 4 + j) * 1024), 16, 0, 0);
    }
  };

  STAGE(0, 0);
  STAGE(1, 1);

  // A fragments: 4 rowgroups x 16 rows, K=128 (64 VGPRs, resident)
  bf16x8 afrag[4][4];
#pragma unroll
  for (int rg = 0; rg < 4; ++rg) {
    const char* ap = pbb + (size_t)(R0 + w * 64 + rg * 16 + c15) * 256 + g * 16;
#pragma unroll
    for (int kk = 0; kk < 4; ++kk)
      afrag[rg][kk] = *reinterpret_cast<const bf16x8*>(ap + kk * 64);
  }

  int rowI[4][4], yrow[4][4];
#pragma unroll
  for (int rg = 0; rg < 4; ++rg)
#pragma unroll
    for (int r = 0; r < 4; ++r) {
      rowI[rg][r] = R0 + w * 64 + rg * 16 + g * 4 + r;
      yrow[rg][r] = y[rowI[rg][r]];
    }

  float mins[4][4], maxd[4][4];
#pragma unroll
  for (int rg = 0; rg < 4; ++rg)
#pragma unroll
    for (int r = 0; r < 4; ++r) { mins[rg][r] = FLT_MAX; maxd[rg][r] = -FLT_MAX; }

#pragma unroll 1
  for (int t = 0; t < TILES; ++t) {
    // counted vmcnt: stage(t) drained (FIFO), stage(t+1)'s 4 loads in flight
    if (t + 1 < TILES) asm volatile("s_waitcnt vmcnt(4)" ::: "memory");
    else               asm volatile("s_waitcnt vmcnt(0)" ::: "memory");
    __builtin_amdgcn_s_barrier();          // all waves' stage(t) landed;
                                           // buf[(t+2)%3] free (was read in t-1)
    if (t + 2 < TILES) STAGE((t + 2) % 3, t + 2);

    const char* Bb = ldsB + (t % 3) * (BN * 256);
    const int ct0 = t * BN;                // col offset within block
#pragma unroll
    for (int s = 0; s < 4; ++s) {
      const int c = s * 16 + c15;
      bf16x8 bf[4];
#pragma unroll
      for (int kk = 0; kk < 4; ++kk) {
        const int off = c * 256 + (((g * 16) | (kk * 64)) ^ (c15 << 4));
        bf[kk] = *reinterpret_cast<const bf16x8*>(Bb + off);
      }
      f32x4 acc[4];
#pragma unroll
      for (int rg = 0; rg < 4; ++rg) acc[rg] = (f32x4){0.f, 0.f, 0.f, 0.f};
#pragma unroll
      for (int kk = 0; kk < 4; ++kk)
#pragma unroll
        for (int rg = 0; rg < 4; ++rg)
          acc[rg] = __builtin_amdgcn_mfma_f32_16x16x32_bf16(afrag[rg][kk], bf[kk],
                                                            acc[rg], 0, 0, 0);
      const int colB = ct0 + c;
      const int col  = C0 + colB;
      const int ycol = ldsY[colB];
#pragma unroll
      for (int rg = 0; rg < 4; ++rg)
#pragma unroll
        for (int r = 0; r < 4; ++r) {
          const float v = acc[rg][r];
          const bool same = (ycol == yrow[rg][r]);
          bool okmin = same;
          if (DIAG) okmin = same && (col != rowI[rg][r]);
          const float cmin = okmin ? v : FLT_MAX;
          const float cmax = same ? -FLT_MAX : v;
          mins[rg][r] = fminf(mins[rg][r], cmin);
          maxd[rg][r] = fmaxf(maxd[rg][r], cmax);
        }
    }
  }

  // butterfly over the 16 col-lanes (bits 0-3)
#pragma unroll
  for (int off = 1; off < 16; off <<= 1)
#pragma unroll
    for (int rg = 0; rg < 4; ++rg)
#pragma unroll
      for (int r = 0; r < 4; ++r) {
        mins[rg][r] = fminf(mins[rg][r], __shfl_xor(mins[rg][r], off, 64));
        maxd[rg][r] = fmaxf(maxd[rg][r], __shfl_xor(maxd[rg][r], off, 64));
      }

  if (c15 == 0) {
#pragma unroll
    for (int rg = 0; rg < 4; ++rg)
#pragma unroll
      for (int r = 0; r < 4; ++r) {
        pmin[(size_t)slot * N + rowI[rg][r]] = mins[rg][r];
        pmax[(size_t)slot * N + rowI[rg][r]] = maxd[rg][r];
      }
  }
}

__global__ __launch_bounds__(256, 2) void margin_main(const u16* __restrict__ Pb,
                                                      const int* __restrict__ y,
                                                      float* __restrict__ pmin,
                                                      float* __restrict__ pmax) {
  __shared__ __align__(16) char ldsB[3][BN * 256];   // 48 KB, 3-deep
  __shared__ int ldsY[COLS_PER_BLOCK];               // 2 KB
  const int R0 = blockIdx.x * BM;
  const int C0 = blockIdx.y * COLS_PER_BLOCK;
  if ((unsigned)(R0 - C0) < (unsigned)COLS_PER_BLOCK)
    pipeline<true>((const char*)Pb, y, pmin, pmax, &ldsB[0][0], ldsY, R0, C0, blockIdx.y);
  else
    pipeline<false>((const char*)Pb, y, pmin, pmax, &ldsB[0][0], ldsY, R0, C0, blockIdx.y);
}

// ------- kernel 3: combine partials + hinge + deterministic final mean -------
// Last-block pattern: each block writes its partial sum, bumps the counter;
// the block observing the final count sums the 32 partials in FIXED index
// order and writes out[0]. Bitwise deterministic across replays.
__global__ __launch_bounds__(256) void loss_final(const float* __restrict__ pmin,
                                                  const float* __restrict__ pmax,
                                                  float* __restrict__ partial,
                                                  int* __restrict__ counter,
                                                  float* __restrict__ out) {
  const int row = blockIdx.x * 256 + threadIdx.x;
  float mn = FLT_MAX, mx = -FLT_MAX;
#pragma unroll
  for (int s = 0; s < NPART; ++s) {            // slot-major: coalesced
    mn = fminf(mn, pmin[(size_t)s * N + row]);
    mx = fmaxf(mx, pmax[(size_t)s * N + row]);
  }
  if (mn == FLT_MAX)  mn = 0.f;                // row has no same-class partner
  if (mx == -FLT_MAX) mx = 0.f;                // row has no diff-class partner
  float loss = fmaxf(0.f, mn + mx + 1.0f);     // TAU = 1.0

#pragma unroll
  for (int off = 32; off >= 1; off >>= 1)
    loss += __shfl_down(loss, off, 64);
  __shared__ float wsum[4];
  if ((threadIdx.x & 63) == 0) wsum[threadIdx.x >> 6] = loss;
  __syncthreads();
  if (threadIdx.x == 0) {
    partial[blockIdx.x] = wsum[0] + wsum[1] + wsum[2] + wsum[3];
    __threadfence();                           // partial visible device-wide
    if (atomicAdd(counter, 1) == LOSS_BLOCKS - 1) {
      __threadfence();                         // acquire all partials
      float tot = 0.f;
#pragma unroll
      for (int b = 0; b < LOSS_BLOCKS; ++b) tot += partial[b];
      out[0] = tot / (float)N;
    }
  }
}

extern "C" void kernel_launch(void* const* d_in, const int* in_sizes, int n_in,
                              void* d_out, int out_size, void* d_ws, size_t ws_size,
                              hipStream_t stream) {
  const float* P = (const float*)d_in[0];
  const int*   y = (const int*)d_in[1];
  float* out = (float*)d_out;

  // ws: Pb (2MB) | pmin (512KB) | pmax (512KB) | partial (128B) | counter
  u16*   Pb      = (u16*)d_ws;
  float* pmin    = (float*)((char*)d_ws + (size_t)N * D * sizeof(u16));
  float* pmax    = pmin + (size_t)N * NPART;
  float* partial = pmax + (size_t)N * NPART;
  int*   counter = (int*)(partial + LOSS_BLOCKS);

  convert_kernel<<<dim3(N * D / 4 / 256), 256, 0, stream>>>(P, Pb, counter);
  margin_main<<<dim3(N / BM, GY), 256, 0, stream>>>(Pb, y, pmin, pmax);
  loss_final<<<dim3(LOSS_BLOCKS), 256, 0, stream>>>(pmin, pmax, partial, counter, out);
}